// Round 3
// baseline (191.685 us; speedup 1.0000x reference)
//
#include <hip/hip_runtime.h>

typedef __attribute__((ext_vector_type(8))) short bf16x8;
typedef __attribute__((ext_vector_type(4))) float f32x4;

#define NB    4096
#define NLINK 33
#define NJ    32
#define KTOT  1024
#define CJ    128
#define NSTEP 32      // K steps of 32 (one MFMA-K each)

// Pre-converted, fragment-swizzled bf16 W (8.4 MB), rebuilt every call.
// Cell ((j*32 + kt)*128 + c)*4 + q  holds bf16x8 of W[j][kt*32 + q*8 + e][c].
// One dwordx4 per MFMA B-fragment. (Layout correctness-verified in R2.)
__device__ short g_Wf[NJ * KTOT * CJ];

// round-to-nearest-even f32 -> bf16 (finite inputs)
static __device__ __forceinline__ short f2bf(float f) {
    unsigned u = __builtin_bit_cast(unsigned, f);
    unsigned r = u + 0x7FFFu + ((u >> 16) & 1u);
    return (short)(r >> 16);
}

__global__ __launch_bounds__(256) void conv_w(const float* __restrict__ W) {
    const int gid = blockIdx.x * 256 + threadIdx.x;   // destination cell index
    const int q  = gid & 3;
    const int c  = (gid >> 2) & 127;
    const int kt = (gid >> 9) & 31;
    const int j  = gid >> 14;
    const float* src = W + ((size_t)j * KTOT + kt * 32 + q * 8) * CJ + c;
    bf16x8 v;
    #pragma unroll
    for (int e = 0; e < 8; ++e) v[e] = f2bf(src[(size_t)e * CJ]);
    reinterpret_cast<bf16x8*>(g_Wf)[gid] = v;
}

// Barrier-free grouped GEMM: one wave owns a 32-row x 128-col output stripe.
// A direct from global f32 (each element read exactly once), B from g_Wf (L2).
__global__ __launch_bounds__(256, 2) void joint_gemm(
    const float* __restrict__ link,
    const float* __restrict__ jf,
    const float* __restrict__ bias,
    const int*   __restrict__ child,
    float* __restrict__ out)
{
    const int tid  = threadIdx.x;
    const int lane = tid & 63;
    const int wave = tid >> 6;     // 0..3
    const int q    = lane >> 4;    // 0..3  (k-subblock)
    const int r    = lane & 15;    // 0..15 (row within 16 / col within 16)

    const int bx = blockIdx.x;
    const int j  = bx & 31;        // j-minor: same-j blocks share an XCD's L2 copy of W
    const int mt = bx >> 5;
    const int row0 = mt * 128 + wave * 32;
    const int cidx = child[j];

    // A: lane (q,r) reads rows row0+r and row0+16+r, 32B at k-offset q*8 floats
    const float* a0 = link + ((size_t)(row0 + r) * NLINK + cidx) * KTOT + q * 8;
    const float* a1 = a0 + (size_t)16 * NLINK * KTOT;

    // B: fragment cells in g_Wf
    const bf16x8* wb = reinterpret_cast<const bf16x8*>(g_Wf);
    const size_t bb = ((size_t)j * 32 * 128 + r) * 4 + q;

    f32x4 acc[2][8] = {};          // 64 f32: rows (mi=0,1), cols (ni=0..7)

    float4 A0[4], A1[4];           // two A step-buffers (16 f32 each)
    bf16x8 B0[8], B1[8];           // two B step-buffers (8 fragments each)

    auto loadA = [&](float4* A, int t) {
        const float4* p0 = reinterpret_cast<const float4*>(a0 + t * 32);
        const float4* p1 = reinterpret_cast<const float4*>(a1 + t * 32);
        A[0] = p0[0]; A[1] = p0[1]; A[2] = p1[0]; A[3] = p1[1];
    };
    auto loadB = [&](bf16x8* Bv, int t) {
        const bf16x8* p = wb + bb + (size_t)t * 512;
        #pragma unroll
        for (int ni = 0; ni < 8; ++ni) Bv[ni] = p[ni * 64];
    };

    loadA(A0, 0); loadB(B0, 0);
    loadA(A1, 1); loadB(B1, 1);

    for (int t = 0; t < NSTEP; t += 2) {
        {   // step t : consume A0/B0, refill for t+2
            bf16x8 af0, af1;
            const float* f = reinterpret_cast<const float*>(A0);
            #pragma unroll
            for (int e = 0; e < 8; ++e) { af0[e] = f2bf(f[e]); af1[e] = f2bf(f[8 + e]); }
            if (t + 2 < NSTEP) loadA(A0, t + 2);
            #pragma unroll
            for (int ni = 0; ni < 8; ++ni) {
                acc[0][ni] = __builtin_amdgcn_mfma_f32_16x16x32_bf16(af0, B0[ni], acc[0][ni], 0, 0, 0);
                acc[1][ni] = __builtin_amdgcn_mfma_f32_16x16x32_bf16(af1, B0[ni], acc[1][ni], 0, 0, 0);
            }
            if (t + 2 < NSTEP) loadB(B0, t + 2);
        }
        {   // step t+1 : consume A1/B1, refill for t+3
            bf16x8 af0, af1;
            const float* f = reinterpret_cast<const float*>(A1);
            #pragma unroll
            for (int e = 0; e < 8; ++e) { af0[e] = f2bf(f[e]); af1[e] = f2bf(f[8 + e]); }
            if (t + 3 < NSTEP) loadA(A1, t + 3);
            #pragma unroll
            for (int ni = 0; ni < 8; ++ni) {
                acc[0][ni] = __builtin_amdgcn_mfma_f32_16x16x32_bf16(af0, B1[ni], acc[0][ni], 0, 0, 0);
                acc[1][ni] = __builtin_amdgcn_mfma_f32_16x16x32_bf16(af1, B1[ni], acc[1][ni], 0, 0, 0);
            }
            if (t + 3 < NSTEP) loadB(B1, t + 3);
        }
    }

    // epilogue: + bias + joint_feats
    float bv[8];
    #pragma unroll
    for (int ni = 0; ni < 8; ++ni) bv[ni] = bias[j * CJ + ni * 16 + r];

    #pragma unroll
    for (int mi = 0; mi < 2; ++mi) {
        #pragma unroll
        for (int rr = 0; rr < 4; ++rr) {
            const int bg = row0 + mi * 16 + q * 4 + rr;
            const size_t ob = ((size_t)bg * NJ + j) * CJ;
            #pragma unroll
            for (int ni = 0; ni < 8; ++ni) {
                const int o = ni * 16 + r;
                out[ob + o] = acc[mi][ni][rr] + bv[ni] + jf[ob + o];
            }
        }
    }
}

extern "C" void kernel_launch(void* const* d_in, const int* in_sizes, int n_in,
                              void* d_out, int out_size, void* d_ws, size_t ws_size,
                              hipStream_t stream) {
    (void)in_sizes; (void)n_in; (void)out_size; (void)d_ws; (void)ws_size;
    const float* link  = (const float*)d_in[0];
    const float* jfeat = (const float*)d_in[1];
    const float* W     = (const float*)d_in[2];
    const float* bias  = (const float*)d_in[3];
    const int*   child = (const int*)d_in[4];
    float* out = (float*)d_out;

    conv_w<<<dim3((NJ * KTOT * CJ / 8) / 256), dim3(256), 0, stream>>>(W);
    joint_gemm<<<dim3(NJ * (NB / 128)), dim3(256), 0, stream>>>(link, jfeat, bias, child, out);
}